// Round 2
// baseline (289.205 us; speedup 1.0000x reference)
//
#include <hip/hip_runtime.h>
#include <hip/hip_bf16.h>

// Problem constants (B,T,H,W,D = 32,16,32,32,64)
#define B_   32
#define T_   16
#define H_   32
#define W_   32
#define D_   64
#define N_   16384          // T*H*W
#define KPT  64             // keys per thread in select kernel (N_/256)
#define BLK  256
#define LOSS_BLOCKS 2048

// ---------------------------------------------------------------------------
// K1: per-row gumbel+marg keys; exact k-th-largest threshold via 3-level
// radix select (12/12/8 bits) on order-preserving uint32 keys; visible mask
// written as 0/1 floats. One block per row. Keys in registers (64/thread).
// Radix select: ~8 barriers total vs 64 for the old 32-round bitwise search.
// ---------------------------------------------------------------------------
__global__ __launch_bounds__(BLK, 1) void select_kernel(
    const float* __restrict__ u_g,
    const float* __restrict__ logp_t,
    const float* __restrict__ logp_h,
    const float* __restrict__ logp_w,
    const float* __restrict__ u_k,
    float* __restrict__ vis_out,     // d_out + 1, [B_*N_] floats (0/1)
    double* __restrict__ invrc,      // ws[0..31] = 1/rc_b
    int* __restrict__ counter)       // zeroed here for K2's ticket
{
    const int b   = blockIdx.x;
    const int tid = threadIdx.x;
    const int lane = tid & 63;
    const int wv   = tid >> 6;

    __shared__ float s_lt[T_], s_lh[H_], s_lw[W_];
    __shared__ int   s_hist[4096];
    __shared__ int   s_wsum[4];
    __shared__ int   s_sel, s_gt, s_eq, s_cnt;
    __shared__ int   s_list[2048];   // rare tie-path index list

    if (tid < T_) s_lt[tid] = logp_t[b*T_ + tid];
    if (tid < H_) s_lh[tid] = logp_h[b*H_ + tid];
    if (tid < W_) s_lw[tid] = logp_w[b*W_ + tid];
    if (b == 0 && tid == 0) *counter = 0;    // for K2's last-block ticket
    __syncthreads();

    // ---- compute keys (order-preserving uint32 of ws) ----
    // NUMERICS LOCKED: stepwise fp32 -logf(-logf(u)), add order (lt+lh)+lw
    // matched the np reference bit-for-bit in R1 (absmax 0.0). Do not alter.
    unsigned keys[KPT];
#pragma unroll
    for (int i = 0; i < KPT; ++i) {
        int   n = i*BLK + tid;
        float u = u_g[b*N_ + n];
        float g = -logf(-logf(u));
        int t = n >> 10;            // / (H_*W_)
        int h = (n >> 5) & 31;
        int w = n & 31;
        float wsv = g + ((s_lt[t] + s_lh[h]) + s_lw[w]);
        unsigned bits = __float_as_uint(wsv);
        keys[i] = (bits & 0x80000000u) ? ~bits : (bits | 0x80000000u);
    }

    // ---- k for this row (np.linspace + fp32 mod/trunc semantics) ----
    float u0    = u_k[0];
    float strat = (b == B_-1) ? 1.0f : (float)((double)b * (1.0/31.0));
    float rate  = fmodf(u0 + strat, 1.0f);
    int   k     = (int)(16384.0f * rate);
    k = k < 1 ? 1 : (k > N_-1 ? N_-1 : k);

    // ---- 3-level radix select, high digits first: 12 / 12 / 8 bits ----
    const int shifts[3] = {20, 8, 0};
    const int widths[3] = {12, 12, 8};
    unsigned prefix   = 0;    // value of key bits above the current level
    int      k_rem    = k;    // rank within the prefix-matching candidate set
    int      count_gt = 0;    // # keys strictly greater than prefix region
    int      count_eq = 0;    // at final level: # keys == thr

    for (int lvl = 0; lvl < 3; ++lvl) {
        const int      sh    = shifts[lvl];
        const int      wd    = widths[lvl];
        const unsigned hs    = (unsigned)(sh + wd);   // bits above this digit
        const int      nbins = 1 << wd;
        const unsigned msk   = (unsigned)(nbins - 1);

        for (int u = tid; u < nbins; u += BLK) s_hist[u] = 0;
        __syncthreads();
#pragma unroll
        for (int i = 0; i < KPT; ++i) {
            if ((unsigned)(((unsigned long long)keys[i]) >> hs) == prefix)
                atomicAdd(&s_hist[(keys[i] >> sh) & msk], 1);
        }
        __syncthreads();

        // suffix scan from the top bucket down; find bucket holding rank k_rem
        const int nb = nbins / BLK;          // 16, 16, 1
        int local = 0;
        for (int j = 0; j < nb; ++j) local += s_hist[tid*nb + j];
        int val = local;                     // wave-level inclusive suffix scan
        for (int off = 1; off < 64; off <<= 1) {
            int v = __shfl_down(val, off);
            if (lane + off < 64) val += v;
        }
        if (lane == 0) s_wsum[wv] = val;
        __syncthreads();
        int above = val - local;             // sum of chunks strictly above mine
        for (int w2 = wv + 1; w2 < 4; ++w2) above += s_wsum[w2];
        for (int j = nb - 1; j >= 0; --j) {  // walk own bins top-down
            int u   = tid*nb + j;
            int cnt = s_hist[u];
            if (above < k_rem && above + cnt >= k_rem) {  // unique finder
                s_sel = u; s_gt = above; s_eq = cnt;
            }
            above += cnt;
        }
        __syncthreads();
        prefix    = (prefix << wd) | (unsigned)s_sel;
        count_gt += s_gt;
        k_rem    -= s_gt;
        count_eq  = s_eq;
        __syncthreads();   // protect s_sel/s_gt/s_eq before next level reuses
    }
    const unsigned thr     = prefix;         // exact key of the k-th largest
    const int      need_eq = k_rem;          // in [1, count_eq] by construction

    // ---- rare tie path: index-ordered selection among equal keys ----
    const bool rare = (count_eq != need_eq);
    if (tid == 0) s_cnt = 0;
    __syncthreads();
    if (rare && count_eq <= 2048) {
#pragma unroll
        for (int i = 0; i < KPT; ++i) {
            if (keys[i] == thr) {
                int slot = atomicAdd(&s_cnt, 1);
                s_list[slot] = i*BLK + tid;
            }
        }
    }
    __syncthreads();

    // ---- write visible mask (coalesced) ----
#pragma unroll
    for (int i = 0; i < KPT; ++i) {
        int n = i*BLK + tid;
        float v;
        if (keys[i] > thr) {
            v = 1.0f;
        } else if (keys[i] == thr) {
            if (!rare || count_eq > 2048) {
                v = 1.0f;                       // all equals visible (common)
            } else {
                int r = 0;
                for (int j = 0; j < count_eq; ++j) r += (s_list[j] < n) ? 1 : 0;
                v = (r < need_eq) ? 1.0f : 0.0f; // first need_eq by index
            }
        } else {
            v = 0.0f;
        }
        vis_out[b*N_ + n] = v;
    }

    if (tid == 0) {
        float rc = (float)(N_ - k) / (float)N_;  // exact: power-of-2 division
        invrc[b] = 1.0 / (double)rc;
    }
}

// ---------------------------------------------------------------------------
// K2: sum score over masked tokens, scaled by 1/rc_b. 16-lane groups read one
// token (64 floats = 16x float4, 256B contiguous) only when masked.
// Per-block partials + last-block-done final reduction (no same-address
// fp64 atomic serialization, no separate finalize launch).
// ---------------------------------------------------------------------------
__global__ __launch_bounds__(BLK, 1) void loss_kernel(
    const float*  __restrict__ score,
    const float*  __restrict__ vis,
    const double* __restrict__ invrc,    // ws[0..31]
    double*       __restrict__ partial,  // ws[32 .. 32+LOSS_BLOCKS)
    int*          __restrict__ counter,  // ticket, zeroed by K1
    float*        __restrict__ out)      // out[0] = loss
{
    const int tid  = threadIdx.x;
    const int lane = tid & 63;
    const int grp  = lane >> 4;          // 4 groups of 16 lanes per wave
    const int sub  = lane & 15;
    const int gw   = (blockIdx.x * BLK + tid) >> 6;            // global wave
    const int totalGroups = ((gridDim.x * BLK) >> 6) << 2;     // waves*4

    double a = 0.0;
    for (int token = gw*4 + grp; token < B_*N_; token += totalGroups) {
        float v = vis[token];
        if (v == 0.0f) {                 // masked -> contributes to loss
            const float4* p = (const float4*)(score + (size_t)token * D_);
            float4 x = p[sub];
            float s = (x.x + x.y) + (x.z + x.w);
            s += __shfl_xor(s, 1);
            s += __shfl_xor(s, 2);
            s += __shfl_xor(s, 4);
            s += __shfl_xor(s, 8);
            if (sub == 0) a += (double)s * invrc[token >> 14];
        }
    }

    for (int off = 32; off > 0; off >>= 1) a += __shfl_down(a, off);
    __shared__ double s_a[4];
    __shared__ int s_flag;
    if (lane == 0) s_a[tid >> 6] = a;
    __syncthreads();
    if (tid == 0) {
        double t = s_a[0] + s_a[1] + s_a[2] + s_a[3];
        partial[blockIdx.x] = t;
        __threadfence();                           // device-scope: cross-XCD
        int ticket = atomicAdd(counter, 1);
        s_flag = (ticket == (int)gridDim.x - 1) ? 1 : 0;
    }
    __syncthreads();
    if (s_flag) {                                  // last block finalizes
        __threadfence();
        double t = 0.0;
        for (int i = tid; i < LOSS_BLOCKS; i += BLK) t += partial[i];
        for (int off = 32; off > 0; off >>= 1) t += __shfl_down(t, off);
        if (lane == 0) s_a[tid >> 6] = t;
        __syncthreads();
        if (tid == 0)
            out[0] = (float)((s_a[0] + s_a[1] + s_a[2] + s_a[3]) / 33554432.0);
    }
}

extern "C" void kernel_launch(void* const* d_in, const int* in_sizes, int n_in,
                              void* d_out, int out_size, void* d_ws, size_t ws_size,
                              hipStream_t stream) {
    const float* u_g    = (const float*)d_in[0];
    const float* logp_t = (const float*)d_in[1];
    const float* logp_h = (const float*)d_in[2];
    const float* logp_w = (const float*)d_in[3];
    const float* u_k    = (const float*)d_in[4];
    const float* score  = (const float*)d_in[5];

    float*  out     = (float*)d_out;     // [0]=loss, [1..B*N]=visible (0/1)
    double* wsd     = (double*)d_ws;
    double* invrc   = wsd;                       // 32 doubles
    double* partial = wsd + 32;                  // LOSS_BLOCKS doubles
    int*    counter = (int*)(wsd + 32 + LOSS_BLOCKS);

    select_kernel<<<B_, BLK, 0, stream>>>(u_g, logp_t, logp_h, logp_w, u_k,
                                          out + 1, invrc, counter);
    loss_kernel<<<LOSS_BLOCKS, BLK, 0, stream>>>(score, out + 1, invrc,
                                                 partial, counter, out);
}

// Round 3
// 253.987 us; speedup vs baseline: 1.1387x; 1.1387x over previous
//
#include <hip/hip_runtime.h>
#include <hip/hip_bf16.h>

// Problem constants (B,T,H,W,D = 32,16,32,32,64)
#define B_   32
#define T_   16
#define H_   32
#define W_   32
#define D_   64
#define N_   16384          // T*H*W
#define KPT  64             // keys per thread in select kernel (N_/256)
#define BLK  256
#define LOSS_BLOCKS 2048
#define LOSS_ITERS  16      // (B_*N_*D_/4) / (LOSS_BLOCKS*BLK)

// ---------------------------------------------------------------------------
// K1: per-row gumbel+marg keys, exact top-k threshold (32-round bitwise
// binary search on order-preserving uint32 keys) — R1 version, absmax 0.0.
// One block per row. Keys in registers (64/thread).
// ---------------------------------------------------------------------------
__global__ __launch_bounds__(BLK, 1) void select_kernel(
    const float* __restrict__ u_g,
    const float* __restrict__ logp_t,
    const float* __restrict__ logp_h,
    const float* __restrict__ logp_w,
    const float* __restrict__ u_k,
    float* __restrict__ vis_out,     // d_out + 1, [B_*N_] floats (0/1)
    double* __restrict__ invrc)      // ws[0..31] = 1/rc_b
{
    const int b   = blockIdx.x;
    const int tid = threadIdx.x;

    __shared__ float s_lt[T_], s_lh[H_], s_lw[W_];
    __shared__ int   s_part[4];
    __shared__ int   s_tot;
    __shared__ int   s_cnt;
    __shared__ int   s_list[2048];   // rare tie-path index list

    if (tid < T_) s_lt[tid] = logp_t[b*T_ + tid];
    if (tid < H_) s_lh[tid] = logp_h[b*H_ + tid];
    if (tid < W_) s_lw[tid] = logp_w[b*W_ + tid];
    __syncthreads();

    // NUMERICS LOCKED: stepwise fp32 -logf(-logf(u)), add order (lt+lh)+lw
    // matched the np reference exactly in R1/R2 (absmax 0.0). Do not alter.
    unsigned keys[KPT];
#pragma unroll
    for (int i = 0; i < KPT; ++i) {
        int   n = i*BLK + tid;
        float u = u_g[b*N_ + n];
        float g = -logf(-logf(u));
        int t = n >> 10;            // / (H_*W_)
        int h = (n >> 5) & 31;
        int w = n & 31;
        float wsv = g + ((s_lt[t] + s_lh[h]) + s_lw[w]);
        unsigned bits = __float_as_uint(wsv);
        keys[i] = (bits & 0x80000000u) ? ~bits : (bits | 0x80000000u);
    }

    // ---- k for this row (np.linspace + fp32 mod/trunc semantics) ----
    float u0    = u_k[0];
    float strat = (b == B_-1) ? 1.0f : (float)((double)b * (1.0/31.0));
    float rate  = fmodf(u0 + strat, 1.0f);
    int   k     = (int)(16384.0f * rate);
    k = k < 1 ? 1 : (k > N_-1 ? N_-1 : k);

    // ---- bitwise binary search for max thr with count(keys >= thr) >= k ----
    unsigned thr = 0u;
    for (int bit = 31; bit >= 0; --bit) {
        unsigned cand = thr | (1u << bit);
        int c = 0;
#pragma unroll
        for (int i = 0; i < KPT; ++i) c += (keys[i] >= cand) ? 1 : 0;
        for (int off = 32; off > 0; off >>= 1) c += __shfl_down(c, off);
        if ((tid & 63) == 0) s_part[tid >> 6] = c;
        __syncthreads();
        if (tid == 0) s_tot = s_part[0] + s_part[1] + s_part[2] + s_part[3];
        __syncthreads();
        if (s_tot >= k) thr = cand;
    }

    // ---- count strictly-greater and equal ----
    {
        int cg = 0, ce = 0;
#pragma unroll
        for (int i = 0; i < KPT; ++i) {
            cg += (keys[i] >  thr) ? 1 : 0;
            ce += (keys[i] == thr) ? 1 : 0;
        }
        int packed = cg | (ce << 16);   // fields <= 16384, no overflow
        for (int off = 32; off > 0; off >>= 1) packed += __shfl_down(packed, off);
        if ((tid & 63) == 0) s_part[tid >> 6] = packed;
        __syncthreads();
        if (tid == 0) s_tot = s_part[0] + s_part[1] + s_part[2] + s_part[3];
        __syncthreads();
    }
    const int tot      = s_tot;
    const int count_gt = tot & 0xffff;
    const int count_eq = tot >> 16;
    const int need_eq  = k - count_gt;   // in [1, count_eq] by construction

    // ---- rare tie path: index-ordered selection among equal keys ----
    const bool rare = (count_eq != need_eq);
    if (tid == 0) s_cnt = 0;
    __syncthreads();
    if (rare && count_eq <= 2048) {
#pragma unroll
        for (int i = 0; i < KPT; ++i) {
            if (keys[i] == thr) {
                int slot = atomicAdd(&s_cnt, 1);
                s_list[slot] = i*BLK + tid;
            }
        }
    }
    __syncthreads();

    // ---- write visible mask (coalesced) ----
#pragma unroll
    for (int i = 0; i < KPT; ++i) {
        int n = i*BLK + tid;
        float v;
        if (keys[i] > thr) {
            v = 1.0f;
        } else if (keys[i] == thr) {
            if (!rare || count_eq > 2048) {
                v = 1.0f;                       // all equals visible (common)
            } else {
                int r = 0;
                for (int j = 0; j < count_eq; ++j) r += (s_list[j] < n) ? 1 : 0;
                v = (r < need_eq) ? 1.0f : 0.0f; // first need_eq by index
            }
        } else {
            v = 0.0f;
        }
        vis_out[b*N_ + n] = v;
    }

    if (tid == 0) {
        float rc = (float)(N_ - k) / (float)N_;  // exact: power-of-2 division
        invrc[b] = 1.0 / (double)rc;
    }
}

// ---------------------------------------------------------------------------
// K2: branchless streaming loss. Every thread reads 16 independent float4s
// of score (wave = 1 KB/instruction, fully unrolled -> 16+ loads in flight),
// multiplies by mask = 1 - vis (exact for m in {0,1}), accumulates in fp64.
// R2's conditional-read version was latency-bound at 372 GB/s (control-
// dependent load chain, ~1 outstanding load/thread). Streaming reads 2x the
// bytes but at full BW.
// ---------------------------------------------------------------------------
__global__ __launch_bounds__(BLK, 1) void loss_kernel(
    const float*  __restrict__ score,
    const float*  __restrict__ vis,      // d_out + 1
    const double* __restrict__ invrc,    // ws[0..31]
    double*       __restrict__ partial)  // ws[32 .. 32+LOSS_BLOCKS)
{
    const int tid = threadIdx.x;
    __shared__ double s_w[B_];
    if (tid < B_) s_w[tid] = invrc[tid];
    __syncthreads();

    const int gtid = blockIdx.x * BLK + tid;     // 0 .. 524287
    const int NT   = LOSS_BLOCKS * BLK;          // 524288 threads
    const float4* s4 = (const float4*)score;     // 8M float4s

    double a = 0.0;
#pragma unroll
    for (int i = 0; i < LOSS_ITERS; ++i) {
        int f = gtid + i * NT;                   // independent address
        float4 x = s4[f];
        float  v = vis[f >> 4];                  // token = f/16 (broadcast-ish)
        float  m = 1.0f - v;                     // mask, exactly 0 or 1
        float  s = ((x.x + x.y) + (x.z + x.w)) * m;
        a += (double)s * s_w[f >> 18];           // b = f / 262144 (uniform)
    }

    for (int off = 32; off > 0; off >>= 1) a += __shfl_down(a, off);
    __shared__ double s_a[4];
    if ((tid & 63) == 0) s_a[tid >> 6] = a;
    __syncthreads();
    if (tid == 0) partial[blockIdx.x] = s_a[0] + s_a[1] + s_a[2] + s_a[3];
}

// ---------------------------------------------------------------------------
// K3: sum 2048 partials, finalize loss = acc / 2^25
// ---------------------------------------------------------------------------
__global__ __launch_bounds__(BLK, 1) void finalize_kernel(
    const double* __restrict__ partial,
    float* __restrict__ out)
{
    const int tid = threadIdx.x;
    double t = 0.0;
    for (int i = tid; i < LOSS_BLOCKS; i += BLK) t += partial[i];
    for (int off = 32; off > 0; off >>= 1) t += __shfl_down(t, off);
    __shared__ double s_a[4];
    if ((tid & 63) == 0) s_a[tid >> 6] = t;
    __syncthreads();
    if (tid == 0)
        out[0] = (float)((s_a[0] + s_a[1] + s_a[2] + s_a[3]) / 33554432.0);
}

extern "C" void kernel_launch(void* const* d_in, const int* in_sizes, int n_in,
                              void* d_out, int out_size, void* d_ws, size_t ws_size,
                              hipStream_t stream) {
    const float* u_g    = (const float*)d_in[0];
    const float* logp_t = (const float*)d_in[1];
    const float* logp_h = (const float*)d_in[2];
    const float* logp_w = (const float*)d_in[3];
    const float* u_k    = (const float*)d_in[4];
    const float* score  = (const float*)d_in[5];

    float*  out     = (float*)d_out;     // [0]=loss, [1..B*N]=visible (0/1)
    double* wsd     = (double*)d_ws;
    double* invrc   = wsd;                       // 32 doubles
    double* partial = wsd + B_;                  // LOSS_BLOCKS doubles

    select_kernel<<<B_, BLK, 0, stream>>>(u_g, logp_t, logp_h, logp_w, u_k,
                                          out + 1, invrc);
    loss_kernel<<<LOSS_BLOCKS, BLK, 0, stream>>>(score, out + 1, invrc, partial);
    finalize_kernel<<<1, BLK, 0, stream>>>(partial, out);
}

// Round 4
// 227.508 us; speedup vs baseline: 1.2712x; 1.1164x over previous
//
#include <hip/hip_runtime.h>
#include <hip/hip_bf16.h>

// Problem constants (B,T,H,W,D = 32,16,32,32,64)
#define B_   32
#define T_   16
#define H_   32
#define W_   32
#define D_   64
#define N_   16384          // T*H*W
#define BLK  256
#define BLK_S 1024          // select block size (16 waves)
#define KPT_S 16            // keys per thread in select (N_/BLK_S)
#define LOSS_BLOCKS 2048
#define LOSS_ITERS  16      // (B_*N_*D_/4) / (LOSS_BLOCKS*BLK)

// ---------------------------------------------------------------------------
// K1: per-row gumbel+marg keys, exact k-th-largest threshold.
// R4: 1024 threads/row, radix-2-bits-per-round binary search (16 rounds),
// ONE barrier per round (parity-double-buffered partials + redundant
// all-thread decision). R1-R3's 32-round/2-barrier version was the largest
// controllable cost (~40-65us inferred; barrier-latency-bound on 32 blocks).
// ---------------------------------------------------------------------------
__global__ __launch_bounds__(BLK_S, 1) void select_kernel(
    const float* __restrict__ u_g,
    const float* __restrict__ logp_t,
    const float* __restrict__ logp_h,
    const float* __restrict__ logp_w,
    const float* __restrict__ u_k,
    float* __restrict__ vis_out,     // d_out + 1, [B_*N_] floats (0/1)
    double* __restrict__ invrc)      // ws[0..31] = 1/rc_b
{
    const int b    = blockIdx.x;
    const int tid  = threadIdx.x;
    const int lane = tid & 63;
    const int wv   = tid >> 6;       // 0..15

    __shared__ float s_lt[T_], s_lh[H_], s_lw[W_];
    __shared__ unsigned long long s_part[2][16];  // parity-double-buffered
    __shared__ int s_cnt;
    __shared__ int s_list[2048];     // rare tie-path index list

    if (tid < T_) s_lt[tid] = logp_t[b*T_ + tid];
    if (tid < H_) s_lh[tid] = logp_h[b*H_ + tid];
    if (tid < W_) s_lw[tid] = logp_w[b*W_ + tid];
    if (tid == 0) s_cnt = 0;
    __syncthreads();

    // NUMERICS LOCKED: stepwise fp32 -logf(-logf(u)), add order (lt+lh)+lw
    // matched the np reference exactly in R1-R3 (absmax 0.0). Do not alter.
    unsigned keys[KPT_S];
#pragma unroll
    for (int i = 0; i < KPT_S; ++i) {
        int   n = i*BLK_S + tid;
        float u = u_g[b*N_ + n];
        float g = -logf(-logf(u));
        int t = n >> 10;            // / (H_*W_)
        int h = (n >> 5) & 31;
        int w = n & 31;
        float wsv = g + ((s_lt[t] + s_lh[h]) + s_lw[w]);
        unsigned bits = __float_as_uint(wsv);
        keys[i] = (bits & 0x80000000u) ? ~bits : (bits | 0x80000000u);
    }

    // ---- k for this row (np.linspace + fp32 mod/trunc semantics) ----
    float u0    = u_k[0];
    float strat = (b == B_-1) ? 1.0f : (float)((double)b * (1.0/31.0));
    float rate  = fmodf(u0 + strat, 1.0f);
    int   k     = (int)(16384.0f * rate);
    k = k < 1 ? 1 : (k > N_-1 ? N_-1 : k);

    // ---- 16 rounds x 2 bits: max thr with count(keys >= thr) >= k ----
    // Per round, count 3 candidates (thr|1<<bp, thr|2<<bp, thr|3<<bp)
    // packed in one u64 (21-bit fields; block totals <= 16384 fit).
    unsigned thr = 0u;
    for (int r = 0; r < 16; ++r) {
        const int bp = 30 - 2*r;
        const unsigned c1 = thr | (1u << bp);
        const unsigned c2 = thr | (2u << bp);
        const unsigned c3 = thr | (3u << bp);
        unsigned long long cnt = 0ull;
#pragma unroll
        for (int i = 0; i < KPT_S; ++i) {
            unsigned kk = keys[i];
            cnt += (kk >= c1 ? 1ull : 0ull)
                 + (kk >= c2 ? (1ull << 21) : 0ull)
                 + (kk >= c3 ? (1ull << 42) : 0ull);
        }
        for (int off = 32; off > 0; off >>= 1) cnt += __shfl_down(cnt, off);
        if (lane == 0) s_part[r & 1][wv] = cnt;
        __syncthreads();
        unsigned long long tot = 0ull;
#pragma unroll
        for (int w2 = 0; w2 < 16; ++w2) tot += s_part[r & 1][w2];
        const int t1 = (int)(tot & 0x1FFFFFull);
        const int t2 = (int)((tot >> 21) & 0x1FFFFFull);
        const int t3 = (int)(tot >> 42);
        const unsigned v = (t3 >= k) ? 3u : (t2 >= k) ? 2u : (t1 >= k) ? 1u : 0u;
        thr |= v << bp;
        // no 2nd barrier: next round writes the OTHER parity buffer, and the
        // intervening barrier protects the same-parity reuse 2 rounds later.
    }

    // ---- count strictly-greater and equal (packed, one barrier) ----
    {
        unsigned long long cnt = 0ull;
#pragma unroll
        for (int i = 0; i < KPT_S; ++i) {
            cnt += (keys[i] >  thr ? 1ull : 0ull)
                 + (keys[i] == thr ? (1ull << 21) : 0ull);
        }
        for (int off = 32; off > 0; off >>= 1) cnt += __shfl_down(cnt, off);
        if (lane == 0) s_part[0][wv] = cnt;
        __syncthreads();
        unsigned long long tot = 0ull;
#pragma unroll
        for (int w2 = 0; w2 < 16; ++w2) tot += s_part[0][w2];
        // store packed totals in thr-adjacent locals via shared recompute
        // (every thread computes the same values redundantly)
        const int count_gt = (int)(tot & 0x1FFFFFull);
        const int count_eq = (int)((tot >> 21) & 0x1FFFFFull);
        const int need_eq  = k - count_gt;   // in [1, count_eq]

        // ---- rare tie path: index-ordered selection among equal keys ----
        const bool rare = (count_eq != need_eq);
        if (rare && count_eq <= 2048) {
#pragma unroll
            for (int i = 0; i < KPT_S; ++i) {
                if (keys[i] == thr) {
                    int slot = atomicAdd(&s_cnt, 1);
                    s_list[slot] = i*BLK_S + tid;
                }
            }
        }
        __syncthreads();

        // ---- write visible mask (coalesced) ----
#pragma unroll
        for (int i = 0; i < KPT_S; ++i) {
            int n = i*BLK_S + tid;
            float v;
            if (keys[i] > thr) {
                v = 1.0f;
            } else if (keys[i] == thr) {
                if (!rare || count_eq > 2048) {
                    v = 1.0f;                        // all equals visible
                } else {
                    int rk = 0;
                    for (int j = 0; j < count_eq; ++j)
                        rk += (s_list[j] < n) ? 1 : 0;
                    v = (rk < need_eq) ? 1.0f : 0.0f; // first need_eq by index
                }
            } else {
                v = 0.0f;
            }
            vis_out[b*N_ + n] = v;
        }
    }

    if (tid == 0) {
        float rc = (float)(N_ - k) / (float)N_;  // exact: power-of-2 division
        invrc[b] = 1.0 / (double)rc;
    }
}

// ---------------------------------------------------------------------------
// K2: loss. R4 hybrid: prefetch all 16 vis predicates (independent loads),
// THEN issue the 16 score float4 loads conditionally -> one latency
// round-trip + full MLP on the ~50% masked tokens (~64MB instead of 130MB).
// R2's inline-conditional version was latency-serialized (372 GB/s); R3's
// unconditional stream read 2x bytes. This takes both wins.
// ---------------------------------------------------------------------------
__global__ __launch_bounds__(BLK, 1) void loss_kernel(
    const float*  __restrict__ score,
    const float*  __restrict__ vis,      // d_out + 1
    const double* __restrict__ invrc,    // ws[0..31]
    double*       __restrict__ partial)  // ws[32 .. 32+LOSS_BLOCKS)
{
    const int tid = threadIdx.x;
    __shared__ double s_w[B_];
    if (tid < B_) s_w[tid] = invrc[tid];
    __syncthreads();

    const int gtid = blockIdx.x * BLK + tid;     // 0 .. 524287
    const int NT   = LOSS_BLOCKS * BLK;          // 524288 threads
    const float4* s4 = (const float4*)score;     // 8M float4s

    // prefetch the 16 mask values (independent, all issue together)
    float vm[LOSS_ITERS];
#pragma unroll
    for (int i = 0; i < LOSS_ITERS; ++i)
        vm[i] = vis[(gtid + i * NT) >> 4];       // 16 lanes share a token

    double a = 0.0;
#pragma unroll
    for (int i = 0; i < LOSS_ITERS; ++i) {
        int f = gtid + i * NT;
        if (vm[i] == 0.0f) {                     // masked -> contributes
            float4 x = s4[f];
            float  s = (x.x + x.y) + (x.z + x.w);
            a += (double)s * s_w[f >> 18];       // b = f / 262144
        }
    }

    for (int off = 32; off > 0; off >>= 1) a += __shfl_down(a, off);
    __shared__ double s_a[4];
    if ((tid & 63) == 0) s_a[tid >> 6] = a;
    __syncthreads();
    if (tid == 0) partial[blockIdx.x] = s_a[0] + s_a[1] + s_a[2] + s_a[3];
}

// ---------------------------------------------------------------------------
// K3: sum 2048 partials, finalize loss = acc / 2^25
// ---------------------------------------------------------------------------
__global__ __launch_bounds__(BLK, 1) void finalize_kernel(
    const double* __restrict__ partial,
    float* __restrict__ out)
{
    const int tid = threadIdx.x;
    double t = 0.0;
    for (int i = tid; i < LOSS_BLOCKS; i += BLK) t += partial[i];
    for (int off = 32; off > 0; off >>= 1) t += __shfl_down(t, off);
    __shared__ double s_a[4];
    if ((tid & 63) == 0) s_a[tid >> 6] = t;
    __syncthreads();
    if (tid == 0)
        out[0] = (float)((s_a[0] + s_a[1] + s_a[2] + s_a[3]) / 33554432.0);
}

extern "C" void kernel_launch(void* const* d_in, const int* in_sizes, int n_in,
                              void* d_out, int out_size, void* d_ws, size_t ws_size,
                              hipStream_t stream) {
    const float* u_g    = (const float*)d_in[0];
    const float* logp_t = (const float*)d_in[1];
    const float* logp_h = (const float*)d_in[2];
    const float* logp_w = (const float*)d_in[3];
    const float* u_k    = (const float*)d_in[4];
    const float* score  = (const float*)d_in[5];

    float*  out     = (float*)d_out;     // [0]=loss, [1..B*N]=visible (0/1)
    double* wsd     = (double*)d_ws;
    double* invrc   = wsd;                       // 32 doubles
    double* partial = wsd + B_;                  // LOSS_BLOCKS doubles

    select_kernel<<<B_, BLK_S, 0, stream>>>(u_g, logp_t, logp_h, logp_w, u_k,
                                            out + 1, invrc);
    loss_kernel<<<LOSS_BLOCKS, BLK, 0, stream>>>(score, out + 1, invrc, partial);
    finalize_kernel<<<1, BLK, 0, stream>>>(partial, out);
}